// Round 12
// baseline (251.483 us; speedup 1.0000x reference)
//
#include <hip/hip_runtime.h>
#include <stdint.h>
#include <stddef.h>

// Problem constants (B=2,S=2048,D=1024,H=16,HD=64)
#define SCALE_LOG2E 11.541560327111707f   // 8 * log2(e): folded into Q projection
#define E8 4194304                        // 4096*1024 plane (elements)
#define M1 1048576                        // 1024*1024 plane

typedef __attribute__((ext_vector_type(8))) _Float16 f16x8;
typedef __attribute__((ext_vector_type(4))) _Float16 f16x4;
typedef __attribute__((ext_vector_type(4))) float f32x4;

#if __has_builtin(__builtin_amdgcn_exp2f)
#define EXP2F(x) __builtin_amdgcn_exp2f(x)
#else
#define EXP2F(x) exp2f(x)
#endif

__device__ __forceinline__ f32x4 mfma_f16(f16x8 a, f16x8 b, f32x4 c) {
  return __builtin_amdgcn_mfma_f32_16x16x32_f16(a, b, c, 0, 0, 0);
}

// Legacy 16x16x16 f16 MFMA: B-operand layout k = qd*4 + j matches the
// 16x16 C-layout row = qd*4 + r, so QK^T scores feed PV directly (no LDS, no shuffles).
__device__ __forceinline__ f32x4 mfma16_f16(f16x4 a, f16x4 b, f32x4 c) {
  return __builtin_amdgcn_mfma_f32_16x16x16f16(a, b, c, 0, 0, 0);
}

// async global->LDS, 16B per lane. LDS dest is wave-uniform base + lane*16.
__device__ __forceinline__ void async16(const void* g, void* lds) {
  __builtin_amdgcn_global_load_lds(
      (const __attribute__((address_space(1))) unsigned int*)g,
      (__attribute__((address_space(3))) unsigned int*)lds, 16, 0, 0);
}

// ---------------- fp32 -> fp16 conversion, W planes only ----------------
// X (query/key/value) is now staged fp32 directly into gemm_qkv via async16 DMA
// (NOT reg-staging -- r7's failure was the vmcnt serialization tax; DMA keeps the
// loads queued in hardware). prep shrinks from 100MB to 25MB of traffic.
__global__ void prep_w(const float* __restrict__ wq, const float* __restrict__ wk,
                       const float* __restrict__ wv, const float* __restrict__ wo,
                       _Float16* __restrict__ Wf) {
  const int gid = blockIdx.x;
  const int z = gid >> 8;                // 256 blocks per plane
  const float* src = (z == 0) ? wq : (z == 1) ? wk : (z == 2) ? wv : wo;
  _Float16* dst = Wf + (size_t)z * M1;
  const int i = (gid & 255) * 1024 + threadIdx.x;
#pragma unroll
  for (int off = 0; off < 1024; off += 256) {
    float4 x = ((const float4*)src)[i + off];
    f16x4 h = {(_Float16)x.x, (_Float16)x.y, (_Float16)x.z, (_Float16)x.w};
    ((f16x4*)dst)[i + off] = h;
  }
}

// ---------------- merged Q/K/V projection: A staged fp32 via async16 DMA ----------------
// z=0: Q (query, bias bq, *SCALE_LOG2E) -> [B,H,S,HD] at Of
// z=1: K (key,   bias bk)               -> [B,H,S,HD] at Of+E8
// z=2: V (value, bias bv)               -> V^T [B,H,HD,S] at Of+2*E8
// grid (32, 8, 3): x = m-tile (XCD-clustering: the 8 n-blocks sharing an A-panel have
// flat id m + 32n + 256z === m (mod 8) -> same XCD L2 -> A fetched once, not 8x).
// A is fp32 in LDS (32KB dbuf), converted f32->f16 at fragment-read time (RNE,
// numerically identical to the old prep path). Chunk pair-swizzle (pair ^= row&3,
// applied on the GLOBAL source so LDS stays linear for DMA) keeps the doubled-width
// A fragment reads at the 8-phase ds_read_b128 minimum. B stays f16 from Wf.
// LDS: 32KB A + 16KB B = 48KB -> 3 blocks/CU, grid 768 = exactly 3/CU.
__global__ __launch_bounds__(256, 3) void gemm_qkv(
    const float* __restrict__ q32, const float* __restrict__ k32,
    const float* __restrict__ v32,
    const _Float16* __restrict__ Wf,    // 4 planes stride M1 (planes 0..2 used here)
    const float* __restrict__ bq, const float* __restrict__ bk,
    const float* __restrict__ bv,
    _Float16* __restrict__ Of)
{
  __shared__ float LAf[8192];           // [2][4096] f32 A dbuf (32 KB); epilogue Ct reuse
  __shared__ _Float16 LB[8192];         // [2][4096] f16 B dbuf (16 KB)
  const int z = blockIdx.z;
  const int tid = threadIdx.x;
  const int lane = tid & 63;
  const int wv = tid >> 6;
  const int wm = wv >> 1, wn = wv & 1;
  const int rl = lane & 15, qd = lane >> 4;
  const int m0 = blockIdx.x * 128, n0 = blockIdx.y * 128;   // x=m, y=n (XCD cluster)

  const float* A32 = (z == 0) ? q32 : (z == 1) ? k32 : v32;
  const _Float16* W0 = Wf + (size_t)z * M1;
  const float* bias = (z == 0) ? bq : (z == 1) ? bk : bv;

  f32x4 acc[4][4];
#pragma unroll
  for (int i = 0; i < 4; i++)
#pragma unroll
    for (int j = 0; j < 4; j++) acc[i][j] = f32x4{0.f, 0.f, 0.f, 0.f};

  const int srow = wv * 32 + (lane >> 2);
  const int scol = (lane & 3) * 8;

  // A: 1024 16B-chunks (4 f32 each), 4 async16/thread. LDS slot cI holds global
  // chunk c = (s&1) | (((s>>1)^(row&3))<<1), s = cI&7 (XOR is self-inverse).
  auto stageA = [&](int k0, int buf) {
#pragma unroll
    for (int j = 0; j < 4; j++) {
      const int cI = j * 256 + tid;
      const int row = cI >> 3, s = cI & 7;
      const int c = (s & 1) | ((((s >> 1) & 3) ^ (row & 3)) << 1);
      async16(A32 + (size_t)(m0 + row) * 1024 + k0 + c * 4,
              &LAf[buf * 4096 + (j * 256 + wv * 64) * 4]);
    }
  };
  // B: f16 from Wf, linear (unchanged r10 pattern)
  auto stageB = [&](int k0, int buf) {
    const _Float16* gb = W0 + (size_t)(n0 + srow) * 1024 + k0 + scol;
    async16(gb, &LB[buf * 4096 + wv * 1024]);
    async16(gb + 16 * 1024, &LB[buf * 4096 + wv * 1024 + 512]);
  };

  stageA(0, 0);
  stageB(0, 0);
  for (int t = 0; t < 32; t++) {
    const int buf = t & 1;
    __syncthreads();                          // DMA(t) drained; all done with buf^1
    if (t + 1 < 32) {
      stageA((t + 1) * 32, buf ^ 1);
      stageB((t + 1) * 32, buf ^ 1);
    }
    f16x8 af[4], bfr[4];
#pragma unroll
    for (int i = 0; i < 4; i++) {
      const int R = wm * 64 + i * 16 + rl;
      const int sp = (qd ^ (R & 3)) << 3;     // stored pair-pos * 8 floats
      f32x4 lo = *(const f32x4*)&LAf[buf * 4096 + R * 32 + sp];
      f32x4 hi = *(const f32x4*)&LAf[buf * 4096 + R * 32 + sp + 4];
      af[i] = f16x8{(_Float16)lo[0], (_Float16)lo[1], (_Float16)lo[2], (_Float16)lo[3],
                    (_Float16)hi[0], (_Float16)hi[1], (_Float16)hi[2], (_Float16)hi[3]};
    }
#pragma unroll
    for (int j = 0; j < 4; j++) bfr[j] = *(const f16x8*)&LB[buf * 4096 + (wn * 64 + j * 16 + rl) * 32 + qd * 8];
#pragma unroll
    for (int i = 0; i < 4; i++)
#pragma unroll
      for (int j = 0; j < 4; j++) acc[i][j] = mfma_f16(af[i], bfr[j], acc[i][j]);
  }

  _Float16* Ct = (_Float16*)LAf;              // epilogue scratch: 16384 f16 = 32 KB

  if (z == 2) {
    // V^T coalesced epilogue via SMEM transpose: Ct[n=128][m=128] f16 (32KB).
    __syncthreads();                          // staging LDS now free
#pragma unroll
    for (int j = 0; j < 4; j++) {
      const int nl = wn * 64 + j * 16 + rl;
      const float bj = bias[n0 + nl];
      const int xsw = (nl & 7) << 4;
#pragma unroll
      for (int i = 0; i < 4; i++) {
        const int ml = wm * 64 + i * 16 + qd * 4;
        f16x4 pk = {(_Float16)(acc[i][j][0] + bj), (_Float16)(acc[i][j][1] + bj),
                    (_Float16)(acc[i][j][2] + bj), (_Float16)(acc[i][j][3] + bj)};
        *(f16x4*)&Ct[nl * 128 + (ml ^ xsw)] = pk;
      }
    }
    __syncthreads();
    const int b = m0 >> 11, s0 = m0 & 2047;
    _Float16* base = Of + 2 * (size_t)E8;
#pragma unroll
    for (int it2 = 0; it2 < 8; it2++) {
      const int n = (it2 * 256 + tid) >> 4;   // 0..127
      const int m8 = (tid & 15) * 8;
      f16x8 vrow = *(const f16x8*)&Ct[n * 128 + (m8 ^ ((n & 7) << 4))];
      const int nn = n0 + n;
      const int hh = nn >> 6, e = nn & 63;
      *(f16x8*)(base + (((size_t)((b * 16 + hh) * 64 + e)) << 11) + s0 + m8) = vrow;
    }
  } else {
    // LDS-transposed coalesced epilogue: Ct[128][128] with qd-xor column swizzle
    const float scl = (z == 0) ? SCALE_LOG2E : 1.0f;
    _Float16* base = Of + (size_t)z * E8;
    __syncthreads();                          // staging LDS now free
#pragma unroll
    for (int j = 0; j < 4; j++) {
      const int nl = wn * 64 + j * 16 + rl;
      const float bj = bias[n0 + nl];
#pragma unroll
      for (int i = 0; i < 4; i++) {
        const int ml = wm * 64 + i * 16 + qd * 4;
        const int np = nl ^ (qd << 4);        // (m>>2)&3 == qd here
#pragma unroll
        for (int r = 0; r < 4; r++)
          Ct[(ml + r) * 128 + np] = (_Float16)((acc[i][j][r] + bj) * scl);
      }
    }
    __syncthreads();
#pragma unroll
    for (int it2 = 0; it2 < 8; it2++) {
      const int m = (it2 * 256 + tid) >> 4;   // 0..127
      const int col8 = (tid & 15) * 8;
      const int np = col8 ^ (((m >> 2) & 3) << 4);
      f16x8 vrow = *(const f16x8*)&Ct[m * 128 + np];
      const int sg = m0 + m;
      const int b = sg >> 11, s = sg & 2047;
      const int nn = n0 + col8;
      const int hh = nn >> 6, e = nn & 63;
      *(f16x8*)(base + (((size_t)((b * 16 + hh) * 2048 + s)) << 6) + e) = vrow;
    }
  }
}

// ---------------- flash attention v14: no-split-KV, 8-wave 128-row blocks ----------------
// grid (32, 16): x = bh, y = q-block (128 rows). 512 blocks x 512 thr = 2 blocks/CU
// = 16 waves/CU. Each staged K/V tile serves 128 q-rows (r6-parity staging traffic).
// Measured r10/r11: attn 66-68us, FETCH 12.3MB, hbm 21MB total -- issue/latency-bound
// interior; memory-structure variants are neutral. bh-XCD clustering: flat id === bh
// (mod 32) -> each head's K/V resident on one XCD L2.
__global__ __launch_bounds__(512, 4) void attn_kernel(
    const _Float16* __restrict__ Qb,   // [B,H,S,HD], pre-scaled by 8*log2e
    const _Float16* __restrict__ Kb,   // [B,H,S,HD]
    const _Float16* __restrict__ Vt,   // [B,H,HD,S]
    _Float16* __restrict__ Xo)         // [B,S,D] final (normalized) attn output
{
  __shared__ _Float16 Ks[2][4096];     // dbuf [64 keys][64 d], xor-swizzled 16B chunks
  __shared__ _Float16 Vs[2][4096];     // dbuf [64 d][64 keys], same swizzle
  const int tid = threadIdx.x;
  const int lane = tid & 63;
  const int wv = tid >> 6;             // 0..7
  const int rl = lane & 15, qd = lane >> 4;
  const int bh = blockIdx.x;
  const int q0 = blockIdx.y * 128 + wv * 16;

  // Q as B-operand fragments [kk]
  f16x8 qf[2];
#pragma unroll
  for (int kk = 0; kk < 2; kk++)
    qf[kk] = *(const f16x8*)(Qb + ((size_t)bh * 2048 + q0 + rl) * 64 + kk * 32 + qd * 8);

  float m_ = -1e30f, l_ = 0.f;         // per-lane l partial
  f32x4 o[4];
#pragma unroll
  for (int jt = 0; jt < 4; jt++) o[jt] = f32x4{0.f, 0.f, 0.f, 0.f};

  // stage K and V tiles (8 KB each): 512 chunks <-> 512 threads, one async16 each.
  // chunk cI = tid: row = tid>>3 (0..63), src chunk c = (tid&7)^(row&7); LDS linear.
  auto stage = [&](int kv, int buf) {
    const int row = tid >> 3;
    const int c = (tid & 7) ^ (row & 7);
    async16(Kb + ((size_t)bh * 2048 + kv + row) * 64 + c * 8, &Ks[buf][wv * 512]);
    async16(Vt + ((size_t)bh * 64 + row) * 2048 + kv + c * 8, &Vs[buf][wv * 512]);
  };

  stage(0, 0);

  for (int t = 0; t < 32; t++) {
    const int buf = t & 1;
    __syncthreads();                           // DMA(t) drained; all done reading buf^1
    if (t + 1 < 32) stage((t + 1) * 64, buf ^ 1);

    // ---- QK^T (S^T): sc[nt]; key = nt*16 + qd*4 + r, q = q0 + rl ----
    f32x4 sc[4];
#pragma unroll
    for (int nt = 0; nt < 4; nt++) sc[nt] = f32x4{0.f, 0.f, 0.f, 0.f};
    __builtin_amdgcn_s_setprio(1);
#pragma unroll
    for (int nt = 0; nt < 4; nt++) {
      const int ro = (nt * 16 + rl) * 64;
#pragma unroll
      for (int kk = 0; kk < 2; kk++) {
        const int cc = (((kk * 4 + qd) ^ (rl & 7)) << 3);
        f16x8 kh = *(const f16x8*)&Ks[buf][ro + cc];
        sc[nt] = mfma_f16(kh, qf[kk], sc[nt]);
      }
    }
    __builtin_amdgcn_s_setprio(0);

    // ---- online softmax (exp2 domain), defer-max (THR=8), pack -> PV B-frags ----
    f16x4 pf[4];
    {
      float a0 = fmaxf(fmaxf(sc[0][0], sc[0][1]), fmaxf(sc[0][2], sc[0][3]));
      float a1 = fmaxf(fmaxf(sc[1][0], sc[1][1]), fmaxf(sc[1][2], sc[1][3]));
      float a2 = fmaxf(fmaxf(sc[2][0], sc[2][1]), fmaxf(sc[2][2], sc[2][3]));
      float a3 = fmaxf(fmaxf(sc[3][0], sc[3][1]), fmaxf(sc[3][2], sc[3][3]));
      float mloc = fmaxf(fmaxf(a0, a1), fmaxf(a2, a3));
      // row max across the 4 qd lanes sharing rl
      float mx = fmaxf(mloc, __shfl_xor(mloc, 16));
      mx = fmaxf(mx, __shfl_xor(mx, 32));
      const float mold = m_;
      float mnew = mold;
      if (__any(mx > mold + 8.f)) {            // T13: rescale only on real growth
        mnew = fmaxf(mold, mx);                // row-consistent
        const float al = EXP2F(mold - mnew);   // 1.0 where unchanged
        l_ *= al;
#pragma unroll
        for (int jt = 0; jt < 4; jt++)
#pragma unroll
          for (int r = 0; r < 4; r++) o[jt][r] *= al;
        m_ = mnew;
      }
      // p bounded by 2^8 (defer threshold), fine in f16
      float sm = 0.f;
#pragma unroll
      for (int nt = 0; nt < 4; nt++) {
        const float p0 = EXP2F(sc[nt][0] - mnew);
        const float p1 = EXP2F(sc[nt][1] - mnew);
        const float p2 = EXP2F(sc[nt][2] - mnew);
        const float p3 = EXP2F(sc[nt][3] - mnew);
        sm += (p0 + p1) + (p2 + p3);
        pf[nt] = f16x4{(_Float16)p0, (_Float16)p1, (_Float16)p2, (_Float16)p3};
      }
      l_ += sm;
    }

    // ---- PV: O^T += V^T · P^T via 16x16x16 (scores in-register, zero LDS) ----
    __builtin_amdgcn_s_setprio(1);
#pragma unroll
    for (int nt = 0; nt < 4; nt++) {
      const int cb = nt * 2 + (qd >> 1);       // V^T column chunk (8 f16) for this lane
#pragma unroll
      for (int jt = 0; jt < 4; jt++) {
        const int row = jt * 16 + rl;          // row&7 == rl&7
        f16x4 vvv = *(const f16x4*)&Vs[buf][row * 64 + ((cb ^ (rl & 7)) << 3) + (qd & 1) * 4];
        o[jt] = mfma16_f16(vvv, pf[nt], o[jt]);
      }
    }
    __builtin_amdgcn_s_setprio(0);
  }

  // epilogue: normalize and write final f16. lane holds d = jt*16 + qd*4 + r
  // for row s = q0 + rl. Xo layout [B,S,D]: base (b*2048+s)*1024 + hh*64.
  {
    float lt = l_ + __shfl_xor(l_, 16);
    lt += __shfl_xor(lt, 32);
    const float inv = 1.0f / lt;
    const int b = bh >> 4, hh = bh & 15;
    const int s = q0 + rl;
    _Float16* xp = Xo + ((size_t)(b * 2048 + s)) * 1024 + hh * 64;
#pragma unroll
    for (int jt = 0; jt < 4; jt++) {
      f16x4 pk = {(_Float16)(o[jt][0] * inv), (_Float16)(o[jt][1] * inv),
                  (_Float16)(o[jt][2] * inv), (_Float16)(o[jt][3] * inv)};
      *(f16x4*)(xp + jt * 16 + qd * 4) = pk;
    }
  }
}

// ---------------- output projection: 64x128 tile, dbuf, fp32 out ----------------
// grid (64, 8): x = m-tile (XCD-clustering: 8 n-blocks sharing an A-panel have
// flat id m + 64n === m (mod 8) -> same XCD L2). r6-proven variant (async16 A
// staging -- r8's reg-staged merge fusion regressed at 2 blocks/CU).
__global__ __launch_bounds__(256, 2) void gemm_out(
    const _Float16* __restrict__ A0,
    const _Float16* __restrict__ W0,
    const float* __restrict__ bias,
    float* __restrict__ out)
{
  __shared__ _Float16 LA[2][2048];   // 64 x 32
  __shared__ _Float16 LB[2][4096];   // 128 x 32
  const int tid = threadIdx.x;
  const int lane = tid & 63;
  const int wv = tid >> 6;
  const int wm = wv >> 1, wn = wv & 1;
  const int rl = lane & 15, qd = lane >> 4;
  const int m0 = blockIdx.x * 64, n0 = blockIdx.y * 128;   // x=m, y=n (XCD cluster)

  f32x4 acc[2][4];
#pragma unroll
  for (int i = 0; i < 2; i++)
#pragma unroll
    for (int j = 0; j < 4; j++) acc[i][j] = f32x4{0.f, 0.f, 0.f, 0.f};

  auto stage = [&](int k0, int buf) {
    {  // A: 256 chunks, 1 per thread
      const int row = tid >> 2, c = tid & 3;
      async16(A0 + (size_t)(m0 + row) * 1024 + k0 + c * 8, &LA[buf][wv * 512]);
    }
#pragma unroll
    for (int it = 0; it < 2; it++) {  // B: 512 chunks, 2 per thread
      const int cI = it * 256 + tid;
      const int row = cI >> 2, c = cI & 3;
      async16(W0 + (size_t)(n0 + row) * 1024 + k0 + c * 8,
              &LB[buf][it * 2048 + wv * 512]);
    }
  };

  stage(0, 0);
  for (int t = 0; t < 32; t++) {
    const int buf = t & 1;
    __syncthreads();
    if (t + 1 < 32) stage((t + 1) * 32, buf ^ 1);
    f16x8 af[2], bfr[4];
#pragma unroll
    for (int i = 0; i < 2; i++) af[i] = *(const f16x8*)&LA[buf][(wm * 32 + i * 16 + rl) * 32 + qd * 8];
#pragma unroll
    for (int j = 0; j < 4; j++) bfr[j] = *(const f16x8*)&LB[buf][(wn * 64 + j * 16 + rl) * 32 + qd * 8];
#pragma unroll
    for (int i = 0; i < 2; i++)
#pragma unroll
      for (int j = 0; j < 4; j++) acc[i][j] = mfma_f16(af[i], bfr[j], acc[i][j]);
  }

#pragma unroll
  for (int j = 0; j < 4; j++) {
    const int nn = n0 + wn * 64 + j * 16 + rl;
    const float bj = bias[nn];
#pragma unroll
    for (int i = 0; i < 2; i++) {
      const int mm = m0 + wm * 32 + i * 16 + qd * 4;
#pragma unroll
      for (int r = 0; r < 4; r++)
        out[(size_t)(mm + r) * 1024 + nn] = acc[i][j][r] + bj;
    }
  }
}

// ---------------- launch ----------------
extern "C" void kernel_launch(void* const* d_in, const int* in_sizes, int n_in,
                              void* d_out, int out_size, void* d_ws, size_t ws_size,
                              hipStream_t stream) {
  const float* query = (const float*)d_in[0];
  const float* key   = (const float*)d_in[1];
  const float* value = (const float*)d_in[2];
  const float* Wq = (const float*)d_in[3];
  const float* bq = (const float*)d_in[4];
  const float* Wk = (const float*)d_in[5];
  const float* bk = (const float*)d_in[6];
  const float* Wv = (const float*)d_in[7];
  const float* bv = (const float*)d_in[8];
  const float* Wo = (const float*)d_in[9];
  const float* bo = (const float*)d_in[10];

  // workspace: f16 region (Xf slot retained but unused; layout unchanged)
  _Float16* ws = (_Float16*)d_ws;
  _Float16* Wf = ws + 3 * (size_t)E8;         // 4*M1: Wq,Wk,Wv,Wo fp16
  _Float16* Qh = Wf + 4 * (size_t)M1;         // E8 [B,H,S,HD] (pre-scaled)
  _Float16* Kh = Qh + (size_t)E8;             // E8 [B,H,S,HD]
  _Float16* Vt = Kh + (size_t)E8;             // E8 [B,H,HD,S]
  _Float16* Xa = Vt + (size_t)E8;             // E8 [B,S,D]

  prep_w<<<1024, 256, 0, stream>>>(Wq, Wk, Wv, Wo, Wf);
  gemm_qkv<<<dim3(32, 8, 3), 256, 0, stream>>>(query, key, value, Wf, bq, bk, bv, Qh);
  attn_kernel<<<dim3(32, 16), 512, 0, stream>>>(Qh, Kh, Vt, Xa);
  gemm_out<<<dim3(64, 8), 256, 0, stream>>>(Xa, Wf + 3 * (size_t)M1, bo, (float*)d_out);
}

// Round 13
// 235.079 us; speedup vs baseline: 1.0698x; 1.0698x over previous
//
#include <hip/hip_runtime.h>
#include <stdint.h>
#include <stddef.h>

// Problem constants (B=2,S=2048,D=1024,H=16,HD=64)
#define SCALE_LOG2E 11.541560327111707f   // 8 * log2(e): folded into Q projection
#define E8 4194304                        // 4096*1024 plane (elements)
#define M1 1048576                        // 1024*1024 plane

typedef __attribute__((ext_vector_type(8))) _Float16 f16x8;
typedef __attribute__((ext_vector_type(4))) _Float16 f16x4;
typedef __attribute__((ext_vector_type(4))) float f32x4;

#if __has_builtin(__builtin_amdgcn_exp2f)
#define EXP2F(x) __builtin_amdgcn_exp2f(x)
#else
#define EXP2F(x) exp2f(x)
#endif

__device__ __forceinline__ f32x4 mfma_f16(f16x8 a, f16x8 b, f32x4 c) {
  return __builtin_amdgcn_mfma_f32_16x16x32_f16(a, b, c, 0, 0, 0);
}

// Legacy 16x16x16 f16 MFMA: B-operand layout k = qd*4 + j matches the
// 16x16 C-layout row = qd*4 + r, so QK^T scores feed PV directly (no LDS, no shuffles).
__device__ __forceinline__ f32x4 mfma16_f16(f16x4 a, f16x4 b, f32x4 c) {
  return __builtin_amdgcn_mfma_f32_16x16x16f16(a, b, c, 0, 0, 0);
}

// async global->LDS, 16B per lane. LDS dest is wave-uniform base + lane*16.
__device__ __forceinline__ void async16(const void* g, void* lds) {
  __builtin_amdgcn_global_load_lds(
      (const __attribute__((address_space(1))) unsigned int*)g,
      (__attribute__((address_space(3))) unsigned int*)lds, 16, 0, 0);
}

// ---------------- merged fp32 -> fp16 conversion (all 7 tensors) ----------------
// 8192 blocks: each thread converts 2 float4s. Ledger: fusing this conversion into
// any GEMM's staging regressed every time (r7, r12: stall signature MfmaUtil ~13%) --
// the dedicated streaming pass at HBM BW (~16us) is the cheapest form of this work.
__global__ void prep_all(const float* __restrict__ q, const float* __restrict__ k,
                         const float* __restrict__ v,
                         const float* __restrict__ wq, const float* __restrict__ wk,
                         const float* __restrict__ wv, const float* __restrict__ wo,
                         _Float16* __restrict__ Xf, _Float16* __restrict__ Wf) {
  const int gid = blockIdx.x;
  const float* src;
  _Float16* dst;
  int i;
  if (gid < 6144) {                      // X planes: 3 x 1M float4, 512 f4/block
    const int z = gid >> 11;
    src = (z == 0) ? q : (z == 1) ? k : v;
    dst = Xf + (size_t)z * E8;
    i = (gid & 2047) * 512 + threadIdx.x;
  } else {                               // W planes: 4 x 256K float4, 512 f4/block
    const int g2 = gid - 6144;
    const int z = g2 >> 9;
    src = (z == 0) ? wq : (z == 1) ? wk : (z == 2) ? wv : wo;
    dst = Wf + (size_t)z * M1;
    i = (g2 & 511) * 512 + threadIdx.x;
  }
#pragma unroll
  for (int off = 0; off < 512; off += 256) {
    float4 x = ((const float4*)src)[i + off];
    f16x4 h = {(_Float16)x.x, (_Float16)x.y, (_Float16)x.z, (_Float16)x.w};
    ((f16x4*)dst)[i + off] = h;
  }
}

// ---------------- merged Q/K/V projection: fp16 GEMM, LDS double-buffered ----------------
// z=0: Q (bias bq, *SCALE_LOG2E) -> [B,H,S,HD] at Of
// z=1: K (bias bk)               -> [B,H,S,HD] at Of+E8
// z=2: V (bias bv)               -> V^T [B,H,HD,S] at Of+2*E8
// grid (32, 8, 3): x = m-tile (XCD-clustering: the 8 n-blocks sharing an A-panel have
// flat id m + 32n + 256z === m (mod 8) -> same XCD L2 -> A fetched once, not 8x).
__global__ __launch_bounds__(256, 3) void gemm_qkv(
    const _Float16* __restrict__ Xf,    // 3 planes stride E8
    const _Float16* __restrict__ Wf,    // 4 planes stride M1
    const float* __restrict__ bq, const float* __restrict__ bk,
    const float* __restrict__ bv,
    _Float16* __restrict__ Of)
{
  __shared__ _Float16 SMEM[16384];      // staging dbuf (2x4096 A + 2x4096 B) / epilogue Ct
  _Float16* LA = SMEM;                  // [2][4096]
  _Float16* LB = SMEM + 8192;           // [2][4096]
  const int z = blockIdx.z;
  const int tid = threadIdx.x;
  const int lane = tid & 63;
  const int wv = tid >> 6;
  const int wm = wv >> 1, wn = wv & 1;
  const int rl = lane & 15, qd = lane >> 4;
  const int m0 = blockIdx.x * 128, n0 = blockIdx.y * 128;   // x=m, y=n (XCD cluster)

  const _Float16* A0 = Xf + (size_t)z * E8;
  const _Float16* W0 = Wf + (size_t)z * M1;
  const float* bias = (z == 0) ? bq : (z == 1) ? bk : bv;

  f32x4 acc[4][4];
#pragma unroll
  for (int i = 0; i < 4; i++)
#pragma unroll
    for (int j = 0; j < 4; j++) acc[i][j] = f32x4{0.f, 0.f, 0.f, 0.f};

  const int srow = wv * 32 + (lane >> 2);
  const int scol = (lane & 3) * 8;

  auto stage = [&](int k0, int buf) {
    const _Float16* ga = A0 + (size_t)(m0 + srow) * 1024 + k0 + scol;
    async16(ga, &LA[buf * 4096 + wv * 1024]);
    async16(ga + 16 * 1024, &LA[buf * 4096 + wv * 1024 + 512]);
    const _Float16* gb = W0 + (size_t)(n0 + srow) * 1024 + k0 + scol;
    async16(gb, &LB[buf * 4096 + wv * 1024]);
    async16(gb + 16 * 1024, &LB[buf * 4096 + wv * 1024 + 512]);
  };

  stage(0, 0);
  for (int t = 0; t < 32; t++) {
    const int buf = t & 1;
    __syncthreads();                          // DMA(t) drained; all done with buf^1
    if (t + 1 < 32) stage((t + 1) * 32, buf ^ 1);
    f16x8 af[4], bfr[4];
#pragma unroll
    for (int i = 0; i < 4; i++) af[i] = *(const f16x8*)&LA[buf * 4096 + (wm * 64 + i * 16 + rl) * 32 + qd * 8];
#pragma unroll
    for (int j = 0; j < 4; j++) bfr[j] = *(const f16x8*)&LB[buf * 4096 + (wn * 64 + j * 16 + rl) * 32 + qd * 8];
#pragma unroll
    for (int i = 0; i < 4; i++)
#pragma unroll
      for (int j = 0; j < 4; j++) acc[i][j] = mfma_f16(af[i], bfr[j], acc[i][j]);
  }

  if (z == 2) {
    // V^T epilogue: Vt[b,h,e,s], 4 contiguous s per store
#pragma unroll
    for (int j = 0; j < 4; j++) {
      const int nn = n0 + wn * 64 + j * 16 + rl;
      const float bj = bias[nn];
      const int hh = nn >> 6, e = nn & 63;
#pragma unroll
      for (int i = 0; i < 4; i++) {
        const int mm = m0 + wm * 64 + i * 16 + qd * 4;
        const int b = mm >> 11, s = mm & 2047;
        f16x4 pk = {(_Float16)(acc[i][j][0] + bj), (_Float16)(acc[i][j][1] + bj),
                    (_Float16)(acc[i][j][2] + bj), (_Float16)(acc[i][j][3] + bj)};
        *(f16x4*)(Of + 2 * (size_t)E8 + (((size_t)((b * 16 + hh) * 64 + e)) << 11) + s) = pk;
      }
    }
  } else {
    // LDS-transposed coalesced epilogue: Ct[128][128] with qd-xor column swizzle
    const float scl = (z == 0) ? SCALE_LOG2E : 1.0f;
    _Float16* base = Of + (size_t)z * E8;
    __syncthreads();                          // staging LDS now free
#pragma unroll
    for (int j = 0; j < 4; j++) {
      const int nl = wn * 64 + j * 16 + rl;
      const float bj = bias[n0 + nl];
#pragma unroll
      for (int i = 0; i < 4; i++) {
        const int ml = wm * 64 + i * 16 + qd * 4;
        const int np = nl ^ (qd << 4);        // (m>>2)&3 == qd here
#pragma unroll
        for (int r = 0; r < 4; r++)
          SMEM[(ml + r) * 128 + np] = (_Float16)((acc[i][j][r] + bj) * scl);
      }
    }
    __syncthreads();
#pragma unroll
    for (int it2 = 0; it2 < 8; it2++) {
      const int m = (it2 * 256 + tid) >> 4;   // 0..127
      const int col8 = (tid & 15) * 8;
      const int np = col8 ^ (((m >> 2) & 3) << 4);
      f16x8 vrow = *(const f16x8*)&SMEM[m * 128 + np];
      const int sg = m0 + m;
      const int b = sg >> 11, s = sg & 2047;
      const int nn = n0 + col8;
      const int hh = nn >> 6, e = nn & 63;
      *(f16x8*)(base + (((size_t)((b * 16 + hh) * 2048 + s)) << 6) + e) = vrow;
    }
  }
}

// ---------------- flash attention v14: no-split-KV, 8-wave 128-row blocks ----------------
// grid (32, 16): x = bh, y = q-block (128 rows). 512 blocks x 512 thr = 2 blocks/CU
// = 16 waves/CU. Each staged K/V tile serves 128 q-rows (r6-parity staging traffic).
// Measured r10: attn 66.4us, FETCH 12.3MB, hbm 21MB total. At 16 waves/CU attn is
// issue/latency-bound (VALU 48 + MFMA 31); memory-structure variants are neutral.
// bh-XCD clustering: flat id === bh (mod 32) -> head's K/V on one XCD L2.
__global__ __launch_bounds__(512, 4) void attn_kernel(
    const _Float16* __restrict__ Qb,   // [B,H,S,HD], pre-scaled by 8*log2e
    const _Float16* __restrict__ Kb,   // [B,H,S,HD]
    const _Float16* __restrict__ Vt,   // [B,H,HD,S]
    _Float16* __restrict__ Xo)         // [B,S,D] final (normalized) attn output
{
  __shared__ _Float16 Ks[2][4096];     // dbuf [64 keys][64 d], xor-swizzled 16B chunks
  __shared__ _Float16 Vs[2][4096];     // dbuf [64 d][64 keys], same swizzle
  const int tid = threadIdx.x;
  const int lane = tid & 63;
  const int wv = tid >> 6;             // 0..7
  const int rl = lane & 15, qd = lane >> 4;
  const int bh = blockIdx.x;
  const int q0 = blockIdx.y * 128 + wv * 16;

  // Q as B-operand fragments [kk]
  f16x8 qf[2];
#pragma unroll
  for (int kk = 0; kk < 2; kk++)
    qf[kk] = *(const f16x8*)(Qb + ((size_t)bh * 2048 + q0 + rl) * 64 + kk * 32 + qd * 8);

  float m_ = -1e30f, l_ = 0.f;         // per-lane l partial
  f32x4 o[4];
#pragma unroll
  for (int jt = 0; jt < 4; jt++) o[jt] = f32x4{0.f, 0.f, 0.f, 0.f};

  // stage K and V tiles (8 KB each): 512 chunks <-> 512 threads, one async16 each.
  // chunk cI = tid: row = tid>>3 (0..63), src chunk c = (tid&7)^(row&7); LDS linear.
  auto stage = [&](int kv, int buf) {
    const int row = tid >> 3;
    const int c = (tid & 7) ^ (row & 7);
    async16(Kb + ((size_t)bh * 2048 + kv + row) * 64 + c * 8, &Ks[buf][wv * 512]);
    async16(Vt + ((size_t)bh * 64 + row) * 2048 + kv + c * 8, &Vs[buf][wv * 512]);
  };

  stage(0, 0);

  for (int t = 0; t < 32; t++) {
    const int buf = t & 1;
    __syncthreads();                           // DMA(t) drained; all done reading buf^1
    if (t + 1 < 32) stage((t + 1) * 64, buf ^ 1);

    // ---- QK^T (S^T): sc[nt]; key = nt*16 + qd*4 + r, q = q0 + rl ----
    f32x4 sc[4];
#pragma unroll
    for (int nt = 0; nt < 4; nt++) sc[nt] = f32x4{0.f, 0.f, 0.f, 0.f};
    __builtin_amdgcn_s_setprio(1);
#pragma unroll
    for (int nt = 0; nt < 4; nt++) {
      const int ro = (nt * 16 + rl) * 64;
#pragma unroll
      for (int kk = 0; kk < 2; kk++) {
        const int cc = (((kk * 4 + qd) ^ (rl & 7)) << 3);
        f16x8 kh = *(const f16x8*)&Ks[buf][ro + cc];
        sc[nt] = mfma_f16(kh, qf[kk], sc[nt]);
      }
    }
    __builtin_amdgcn_s_setprio(0);

    // ---- online softmax (exp2 domain), defer-max (THR=8), pack -> PV B-frags ----
    f16x4 pf[4];
    {
      float a0 = fmaxf(fmaxf(sc[0][0], sc[0][1]), fmaxf(sc[0][2], sc[0][3]));
      float a1 = fmaxf(fmaxf(sc[1][0], sc[1][1]), fmaxf(sc[1][2], sc[1][3]));
      float a2 = fmaxf(fmaxf(sc[2][0], sc[2][1]), fmaxf(sc[2][2], sc[2][3]));
      float a3 = fmaxf(fmaxf(sc[3][0], sc[3][1]), fmaxf(sc[3][2], sc[3][3]));
      float mloc = fmaxf(fmaxf(a0, a1), fmaxf(a2, a3));
      // row max across the 4 qd lanes sharing rl
      float mx = fmaxf(mloc, __shfl_xor(mloc, 16));
      mx = fmaxf(mx, __shfl_xor(mx, 32));
      const float mold = m_;
      float mnew = mold;
      if (__any(mx > mold + 8.f)) {            // T13: rescale only on real growth
        mnew = fmaxf(mold, mx);                // row-consistent
        const float al = EXP2F(mold - mnew);   // 1.0 where unchanged
        l_ *= al;
#pragma unroll
        for (int jt = 0; jt < 4; jt++)
#pragma unroll
          for (int r = 0; r < 4; r++) o[jt][r] *= al;
        m_ = mnew;
      }
      // p bounded by 2^8 (defer threshold), fine in f16
      float sm = 0.f;
#pragma unroll
      for (int nt = 0; nt < 4; nt++) {
        const float p0 = EXP2F(sc[nt][0] - mnew);
        const float p1 = EXP2F(sc[nt][1] - mnew);
        const float p2 = EXP2F(sc[nt][2] - mnew);
        const float p3 = EXP2F(sc[nt][3] - mnew);
        sm += (p0 + p1) + (p2 + p3);
        pf[nt] = f16x4{(_Float16)p0, (_Float16)p1, (_Float16)p2, (_Float16)p3};
      }
      l_ += sm;
    }

    // ---- PV: O^T += V^T · P^T via 16x16x16 (scores in-register, zero LDS) ----
    __builtin_amdgcn_s_setprio(1);
#pragma unroll
    for (int nt = 0; nt < 4; nt++) {
      const int cb = nt * 2 + (qd >> 1);       // V^T column chunk (8 f16) for this lane
#pragma unroll
      for (int jt = 0; jt < 4; jt++) {
        const int row = jt * 16 + rl;          // row&7 == rl&7
        f16x4 vvv = *(const f16x4*)&Vs[buf][row * 64 + ((cb ^ (rl & 7)) << 3) + (qd & 1) * 4];
        o[jt] = mfma16_f16(vvv, pf[nt], o[jt]);
      }
    }
    __builtin_amdgcn_s_setprio(0);
  }

  // epilogue: normalize and write final f16. lane holds d = jt*16 + qd*4 + r
  // for row s = q0 + rl. Xo layout [B,S,D]: base (b*2048+s)*1024 + hh*64.
  {
    float lt = l_ + __shfl_xor(l_, 16);
    lt += __shfl_xor(lt, 32);
    const float inv = 1.0f / lt;
    const int b = bh >> 4, hh = bh & 15;
    const int s = q0 + rl;
    _Float16* xp = Xo + ((size_t)(b * 2048 + s)) * 1024 + hh * 64;
#pragma unroll
    for (int jt = 0; jt < 4; jt++) {
      f16x4 pk = {(_Float16)(o[jt][0] * inv), (_Float16)(o[jt][1] * inv),
                  (_Float16)(o[jt][2] * inv), (_Float16)(o[jt][3] * inv)};
      *(f16x4*)(xp + jt * 16 + qd * 4) = pk;
    }
  }
}

// ---------------- output projection: 64x128 tile, dbuf, fp32 out ----------------
// grid (64, 8): x = m-tile (XCD-clustering: 8 n-blocks sharing an A-panel have
// flat id m + 64n === m (mod 8) -> same XCD L2). r6-proven variant (async16 A
// staging -- r8's reg-staged merge fusion regressed at 2 blocks/CU).
__global__ __launch_bounds__(256, 2) void gemm_out(
    const _Float16* __restrict__ A0,
    const _Float16* __restrict__ W0,
    const float* __restrict__ bias,
    float* __restrict__ out)
{
  __shared__ _Float16 LA[2][2048];   // 64 x 32
  __shared__ _Float16 LB[2][4096];   // 128 x 32
  const int tid = threadIdx.x;
  const int lane = tid & 63;
  const int wv = tid >> 6;
  const int wm = wv >> 1, wn = wv & 1;
  const int rl = lane & 15, qd = lane >> 4;
  const int m0 = blockIdx.x * 64, n0 = blockIdx.y * 128;   // x=m, y=n (XCD cluster)

  f32x4 acc[2][4];
#pragma unroll
  for (int i = 0; i < 2; i++)
#pragma unroll
    for (int j = 0; j < 4; j++) acc[i][j] = f32x4{0.f, 0.f, 0.f, 0.f};

  auto stage = [&](int k0, int buf) {
    {  // A: 256 chunks, 1 per thread
      const int row = tid >> 2, c = tid & 3;
      async16(A0 + (size_t)(m0 + row) * 1024 + k0 + c * 8, &LA[buf][wv * 512]);
    }
#pragma unroll
    for (int it = 0; it < 2; it++) {  // B: 512 chunks, 2 per thread
      const int cI = it * 256 + tid;
      const int row = cI >> 2, c = cI & 3;
      async16(W0 + (size_t)(n0 + row) * 1024 + k0 + c * 8,
              &LB[buf][it * 2048 + wv * 512]);
    }
  };

  stage(0, 0);
  for (int t = 0; t < 32; t++) {
    const int buf = t & 1;
    __syncthreads();
    if (t + 1 < 32) stage((t + 1) * 32, buf ^ 1);
    f16x8 af[2], bfr[4];
#pragma unroll
    for (int i = 0; i < 2; i++) af[i] = *(const f16x8*)&LA[buf][(wm * 32 + i * 16 + rl) * 32 + qd * 8];
#pragma unroll
    for (int j = 0; j < 4; j++) bfr[j] = *(const f16x8*)&LB[buf][(wn * 64 + j * 16 + rl) * 32 + qd * 8];
#pragma unroll
    for (int i = 0; i < 2; i++)
#pragma unroll
      for (int j = 0; j < 4; j++) acc[i][j] = mfma_f16(af[i], bfr[j], acc[i][j]);
  }

#pragma unroll
  for (int j = 0; j < 4; j++) {
    const int nn = n0 + wn * 64 + j * 16 + rl;
    const float bj = bias[nn];
#pragma unroll
    for (int i = 0; i < 2; i++) {
      const int mm = m0 + wm * 32 + i * 16 + qd * 4;
#pragma unroll
      for (int r = 0; r < 4; r++)
        out[(size_t)(mm + r) * 1024 + nn] = acc[i][j][r] + bj;
    }
  }
}

// ---------------- launch ----------------
extern "C" void kernel_launch(void* const* d_in, const int* in_sizes, int n_in,
                              void* d_out, int out_size, void* d_ws, size_t ws_size,
                              hipStream_t stream) {
  const float* query = (const float*)d_in[0];
  const float* key   = (const float*)d_in[1];
  const float* value = (const float*)d_in[2];
  const float* Wq = (const float*)d_in[3];
  const float* bq = (const float*)d_in[4];
  const float* Wk = (const float*)d_in[5];
  const float* bk = (const float*)d_in[6];
  const float* Wv = (const float*)d_in[7];
  const float* bv = (const float*)d_in[8];
  const float* Wo = (const float*)d_in[9];
  const float* bo = (const float*)d_in[10];

  // workspace: f16 region 67 MB
  _Float16* ws = (_Float16*)d_ws;
  _Float16* Xf = ws;                          // 3*E8: query,key,value fp16
  _Float16* Wf = ws + 3 * (size_t)E8;         // 4*M1: Wq,Wk,Wv,Wo fp16
  _Float16* Qh = Wf + 4 * (size_t)M1;         // E8 [B,H,S,HD] (pre-scaled)
  _Float16* Kh = Qh + (size_t)E8;             // E8 [B,H,S,HD]
  _Float16* Vt = Kh + (size_t)E8;             // E8 [B,H,HD,S]
  _Float16* Xa = Vt + (size_t)E8;             // E8 [B,S,D]

  prep_all<<<8192, 256, 0, stream>>>(query, key, value, Wq, Wk, Wv, Wo, Xf, Wf);
  gemm_qkv<<<dim3(32, 8, 3), 256, 0, stream>>>(Xf, Wf, bq, bk, bv, Qh);
  attn_kernel<<<dim3(32, 16), 512, 0, stream>>>(Qh, Kh, Vt, Xa);
  gemm_out<<<dim3(64, 8), 256, 0, stream>>>(Xa, Wf + 3 * (size_t)M1, bo, (float*)d_out);
}

// Round 14
// 228.422 us; speedup vs baseline: 1.1010x; 1.0291x over previous
//
#include <hip/hip_runtime.h>
#include <stdint.h>
#include <stddef.h>

// Problem constants (B=2,S=2048,D=1024,H=16,HD=64)
#define SCALE_LOG2E 11.541560327111707f   // 8 * log2(e): folded into Q projection
#define E8 4194304                        // 4096*1024 plane (elements)
#define M1 1048576                        // 1024*1024 plane

typedef __attribute__((ext_vector_type(8))) _Float16 f16x8;
typedef __attribute__((ext_vector_type(4))) _Float16 f16x4;
typedef __attribute__((ext_vector_type(4))) float f32x4;

#if __has_builtin(__builtin_amdgcn_exp2f)
#define EXP2F(x) __builtin_amdgcn_exp2f(x)
#else
#define EXP2F(x) exp2f(x)
#endif

__device__ __forceinline__ f32x4 mfma_f16(f16x8 a, f16x8 b, f32x4 c) {
  return __builtin_amdgcn_mfma_f32_16x16x32_f16(a, b, c, 0, 0, 0);
}

// Legacy 16x16x16 f16 MFMA: B-operand layout k = qd*4 + j matches the
// 16x16 C-layout row = qd*4 + r, so QK^T scores feed PV directly (no LDS, no shuffles).
__device__ __forceinline__ f32x4 mfma16_f16(f16x4 a, f16x4 b, f32x4 c) {
  return __builtin_amdgcn_mfma_f32_16x16x16f16(a, b, c, 0, 0, 0);
}

// async global->LDS, 16B per lane. LDS dest is wave-uniform base + lane*16.
__device__ __forceinline__ void async16(const void* g, void* lds) {
  __builtin_amdgcn_global_load_lds(
      (const __attribute__((address_space(1))) unsigned int*)g,
      (__attribute__((address_space(3))) unsigned int*)lds, 16, 0, 0);
}

// ---------------- merged fp32 -> fp16 conversion (all 7 tensors) ----------------
// 8192 blocks: each thread converts 2 float4s. Ledger: fusing this conversion into
// any GEMM's staging regressed every time (r7, r12: stall signature MfmaUtil ~13%) --
// the dedicated streaming pass at HBM BW (~16us) is the cheapest form of this work.
__global__ void prep_all(const float* __restrict__ q, const float* __restrict__ k,
                         const float* __restrict__ v,
                         const float* __restrict__ wq, const float* __restrict__ wk,
                         const float* __restrict__ wv, const float* __restrict__ wo,
                         _Float16* __restrict__ Xf, _Float16* __restrict__ Wf) {
  const int gid = blockIdx.x;
  const float* src;
  _Float16* dst;
  int i;
  if (gid < 6144) {                      // X planes: 3 x 1M float4, 512 f4/block
    const int z = gid >> 11;
    src = (z == 0) ? q : (z == 1) ? k : v;
    dst = Xf + (size_t)z * E8;
    i = (gid & 2047) * 512 + threadIdx.x;
  } else {                               // W planes: 4 x 256K float4, 512 f4/block
    const int g2 = gid - 6144;
    const int z = g2 >> 9;
    src = (z == 0) ? wq : (z == 1) ? wk : (z == 2) ? wv : wo;
    dst = Wf + (size_t)z * M1;
    i = (g2 & 511) * 512 + threadIdx.x;
  }
#pragma unroll
  for (int off = 0; off < 512; off += 256) {
    float4 x = ((const float4*)src)[i + off];
    f16x4 h = {(_Float16)x.x, (_Float16)x.y, (_Float16)x.z, (_Float16)x.w};
    ((f16x4*)dst)[i + off] = h;
  }
}

// ---------------- merged Q/K/V projection: fp16 GEMM, LDS double-buffered ----------------
// z=0: Q (bias bq, *SCALE_LOG2E) -> [B,H,S,HD] at Of
// z=1: K (bias bk)               -> [B,H,S,HD] at Of+E8
// z=2: V (bias bv)               -> V^T [B,H,HD,S] at Of+2*E8
// grid (32, 8, 3): x = m-tile (XCD-clustering: the 8 n-blocks sharing an A-panel have
// flat id m + 32n + 256z === m (mod 8) -> same XCD L2 -> A fetched once, not 8x).
__global__ __launch_bounds__(256, 3) void gemm_qkv(
    const _Float16* __restrict__ Xf,    // 3 planes stride E8
    const _Float16* __restrict__ Wf,    // 4 planes stride M1
    const float* __restrict__ bq, const float* __restrict__ bk,
    const float* __restrict__ bv,
    _Float16* __restrict__ Of)
{
  __shared__ _Float16 SMEM[16384];      // staging dbuf (2x4096 A + 2x4096 B) / epilogue Ct
  _Float16* LA = SMEM;                  // [2][4096]
  _Float16* LB = SMEM + 8192;           // [2][4096]
  const int z = blockIdx.z;
  const int tid = threadIdx.x;
  const int lane = tid & 63;
  const int wv = tid >> 6;
  const int wm = wv >> 1, wn = wv & 1;
  const int rl = lane & 15, qd = lane >> 4;
  const int m0 = blockIdx.x * 128, n0 = blockIdx.y * 128;   // x=m, y=n (XCD cluster)

  const _Float16* A0 = Xf + (size_t)z * E8;
  const _Float16* W0 = Wf + (size_t)z * M1;
  const float* bias = (z == 0) ? bq : (z == 1) ? bk : bv;

  f32x4 acc[4][4];
#pragma unroll
  for (int i = 0; i < 4; i++)
#pragma unroll
    for (int j = 0; j < 4; j++) acc[i][j] = f32x4{0.f, 0.f, 0.f, 0.f};

  const int srow = wv * 32 + (lane >> 2);
  const int scol = (lane & 3) * 8;

  auto stage = [&](int k0, int buf) {
    const _Float16* ga = A0 + (size_t)(m0 + srow) * 1024 + k0 + scol;
    async16(ga, &LA[buf * 4096 + wv * 1024]);
    async16(ga + 16 * 1024, &LA[buf * 4096 + wv * 1024 + 512]);
    const _Float16* gb = W0 + (size_t)(n0 + srow) * 1024 + k0 + scol;
    async16(gb, &LB[buf * 4096 + wv * 1024]);
    async16(gb + 16 * 1024, &LB[buf * 4096 + wv * 1024 + 512]);
  };

  stage(0, 0);
  for (int t = 0; t < 32; t++) {
    const int buf = t & 1;
    __syncthreads();                          // DMA(t) drained; all done with buf^1
    if (t + 1 < 32) stage((t + 1) * 32, buf ^ 1);
    f16x8 af[4], bfr[4];
#pragma unroll
    for (int i = 0; i < 4; i++) af[i] = *(const f16x8*)&LA[buf * 4096 + (wm * 64 + i * 16 + rl) * 32 + qd * 8];
#pragma unroll
    for (int j = 0; j < 4; j++) bfr[j] = *(const f16x8*)&LB[buf * 4096 + (wn * 64 + j * 16 + rl) * 32 + qd * 8];
#pragma unroll
    for (int i = 0; i < 4; i++)
#pragma unroll
      for (int j = 0; j < 4; j++) acc[i][j] = mfma_f16(af[i], bfr[j], acc[i][j]);
  }

  if (z == 2) {
    // V^T epilogue: Vt[b,h,e,s], 4 contiguous s per store
#pragma unroll
    for (int j = 0; j < 4; j++) {
      const int nn = n0 + wn * 64 + j * 16 + rl;
      const float bj = bias[nn];
      const int hh = nn >> 6, e = nn & 63;
#pragma unroll
      for (int i = 0; i < 4; i++) {
        const int mm = m0 + wm * 64 + i * 16 + qd * 4;
        const int b = mm >> 11, s = mm & 2047;
        f16x4 pk = {(_Float16)(acc[i][j][0] + bj), (_Float16)(acc[i][j][1] + bj),
                    (_Float16)(acc[i][j][2] + bj), (_Float16)(acc[i][j][3] + bj)};
        *(f16x4*)(Of + 2 * (size_t)E8 + (((size_t)((b * 16 + hh) * 64 + e)) << 11) + s) = pk;
      }
    }
  } else {
    // LDS-transposed coalesced epilogue: Ct[128][128] with qd-xor column swizzle
    const float scl = (z == 0) ? SCALE_LOG2E : 1.0f;
    _Float16* base = Of + (size_t)z * E8;
    __syncthreads();                          // staging LDS now free
#pragma unroll
    for (int j = 0; j < 4; j++) {
      const int nl = wn * 64 + j * 16 + rl;
      const float bj = bias[n0 + nl];
#pragma unroll
      for (int i = 0; i < 4; i++) {
        const int ml = wm * 64 + i * 16 + qd * 4;
        const int np = nl ^ (qd << 4);        // (m>>2)&3 == qd here
#pragma unroll
        for (int r = 0; r < 4; r++)
          SMEM[(ml + r) * 128 + np] = (_Float16)((acc[i][j][r] + bj) * scl);
      }
    }
    __syncthreads();
#pragma unroll
    for (int it2 = 0; it2 < 8; it2++) {
      const int m = (it2 * 256 + tid) >> 4;   // 0..127
      const int col8 = (tid & 15) * 8;
      const int np = col8 ^ (((m >> 2) & 3) << 4);
      f16x8 vrow = *(const f16x8*)&SMEM[m * 128 + np];
      const int sg = m0 + m;
      const int b = sg >> 11, s = sg & 2047;
      const int nn = n0 + col8;
      const int hh = nn >> 6, e = nn & 63;
      *(f16x8*)(base + (((size_t)((b * 16 + hh) * 2048 + s)) << 6) + e) = vrow;
    }
  }
}

// ---------------- flash attention v15: v14 + T4 counted-vmcnt (non-draining barriers) ----------------
// grid (32, 16): x = bh, y = q-block (128 rows). 512 blocks x 512 thr = 2 blocks/CU
// = 16 waves/CU. v14 structure, but the per-iteration __syncthreads (which drains
// vmcnt to 0 -- the m97-structure's ~20% stall) is replaced by raw s_barrier with a
// COUNTED s_waitcnt vmcnt(2): triple-buffered K/V (48KB), stage(t+2) issued each
// iter, its 2 loads stay in flight ACROSS the barrier while stage(t+1) is verified
// complete. WAR safety: reads of buf(t-1) are lgkm-waited before iter t-1's barrier
// (every ds_read feeds an MFMA in-iteration), and only iter t's DMA targets that
// buffer. bh-XCD clustering retained (FETCH 12.3MB measured).
__global__ __launch_bounds__(512, 4) void attn_kernel(
    const _Float16* __restrict__ Qb,   // [B,H,S,HD], pre-scaled by 8*log2e
    const _Float16* __restrict__ Kb,   // [B,H,S,HD]
    const _Float16* __restrict__ Vt,   // [B,H,HD,S]
    _Float16* __restrict__ Xo)         // [B,S,D] final (normalized) attn output
{
  __shared__ _Float16 Ks[3][4096];     // tbuf [64 keys][64 d], xor-swizzled 16B chunks
  __shared__ _Float16 Vs[3][4096];     // tbuf [64 d][64 keys], same swizzle
  const int tid = threadIdx.x;
  const int lane = tid & 63;
  const int wv = tid >> 6;             // 0..7
  const int rl = lane & 15, qd = lane >> 4;
  const int bh = blockIdx.x;
  const int q0 = blockIdx.y * 128 + wv * 16;

  // Q as B-operand fragments [kk]
  f16x8 qf[2];
#pragma unroll
  for (int kk = 0; kk < 2; kk++)
    qf[kk] = *(const f16x8*)(Qb + ((size_t)bh * 2048 + q0 + rl) * 64 + kk * 32 + qd * 8);

  float m_ = -1e30f, l_ = 0.f;         // per-lane l partial
  f32x4 o[4];
#pragma unroll
  for (int jt = 0; jt < 4; jt++) o[jt] = f32x4{0.f, 0.f, 0.f, 0.f};

  // stage K and V tiles (8 KB each): 512 chunks <-> 512 threads, one async16 each.
  // chunk cI = tid: row = tid>>3 (0..63), src chunk c = (tid&7)^(row&7); LDS linear.
  auto stage = [&](int kv, int buf) {
    const int row = tid >> 3;
    const int c = (tid & 7) ^ (row & 7);
    async16(Kb + ((size_t)bh * 2048 + kv + row) * 64 + c * 8, &Ks[buf][wv * 512]);
    async16(Vt + ((size_t)bh * 64 + row) * 2048 + kv + c * 8, &Vs[buf][wv * 512]);
  };

  stage(0, 0);                          // tile 0 -> buf 0 (2 loads)
  stage(64, 1);                         // tile 1 -> buf 1 (2 loads)
  asm volatile("s_waitcnt vmcnt(2)" ::: "memory");  // tile0 (+Q) done; tile1 in flight
  __builtin_amdgcn_s_barrier();

  for (int t = 0; t < 32; t++) {
    const int buf = t % 3;
    if (t < 30) stage((t + 2) * 64, (t + 2) % 3);   // 2 more loads in flight

    // ---- QK^T (S^T): sc[nt]; key = nt*16 + qd*4 + r, q = q0 + rl ----
    f32x4 sc[4];
#pragma unroll
    for (int nt = 0; nt < 4; nt++) sc[nt] = f32x4{0.f, 0.f, 0.f, 0.f};
    __builtin_amdgcn_s_setprio(1);
#pragma unroll
    for (int nt = 0; nt < 4; nt++) {
      const int ro = (nt * 16 + rl) * 64;
#pragma unroll
      for (int kk = 0; kk < 2; kk++) {
        const int cc = (((kk * 4 + qd) ^ (rl & 7)) << 3);
        f16x8 kh = *(const f16x8*)&Ks[buf][ro + cc];
        sc[nt] = mfma_f16(kh, qf[kk], sc[nt]);
      }
    }
    __builtin_amdgcn_s_setprio(0);

    // ---- online softmax (exp2 domain), defer-max (THR=8), pack -> PV B-frags ----
    f16x4 pf[4];
    {
      float a0 = fmaxf(fmaxf(sc[0][0], sc[0][1]), fmaxf(sc[0][2], sc[0][3]));
      float a1 = fmaxf(fmaxf(sc[1][0], sc[1][1]), fmaxf(sc[1][2], sc[1][3]));
      float a2 = fmaxf(fmaxf(sc[2][0], sc[2][1]), fmaxf(sc[2][2], sc[2][3]));
      float a3 = fmaxf(fmaxf(sc[3][0], sc[3][1]), fmaxf(sc[3][2], sc[3][3]));
      float mloc = fmaxf(fmaxf(a0, a1), fmaxf(a2, a3));
      // row max across the 4 qd lanes sharing rl
      float mx = fmaxf(mloc, __shfl_xor(mloc, 16));
      mx = fmaxf(mx, __shfl_xor(mx, 32));
      const float mold = m_;
      float mnew = mold;
      if (__any(mx > mold + 8.f)) {            // T13: rescale only on real growth
        mnew = fmaxf(mold, mx);                // row-consistent
        const float al = EXP2F(mold - mnew);   // 1.0 where unchanged
        l_ *= al;
#pragma unroll
        for (int jt = 0; jt < 4; jt++)
#pragma unroll
          for (int r = 0; r < 4; r++) o[jt][r] *= al;
        m_ = mnew;
      }
      // p bounded by 2^8 (defer threshold), fine in f16
      float sm = 0.f;
#pragma unroll
      for (int nt = 0; nt < 4; nt++) {
        const float p0 = EXP2F(sc[nt][0] - mnew);
        const float p1 = EXP2F(sc[nt][1] - mnew);
        const float p2 = EXP2F(sc[nt][2] - mnew);
        const float p3 = EXP2F(sc[nt][3] - mnew);
        sm += (p0 + p1) + (p2 + p3);
        pf[nt] = f16x4{(_Float16)p0, (_Float16)p1, (_Float16)p2, (_Float16)p3};
      }
      l_ += sm;
    }

    // ---- PV: O^T += V^T · P^T via 16x16x16 (scores in-register, zero LDS) ----
    __builtin_amdgcn_s_setprio(1);
#pragma unroll
    for (int nt = 0; nt < 4; nt++) {
      const int cb = nt * 2 + (qd >> 1);       // V^T column chunk (8 f16) for this lane
#pragma unroll
      for (int jt = 0; jt < 4; jt++) {
        const int row = jt * 16 + rl;          // row&7 == rl&7
        f16x4 vvv = *(const f16x4*)&Vs[buf][row * 64 + ((cb ^ (rl & 7)) << 3) + (qd & 1) * 4];
        o[jt] = mfma16_f16(vvv, pf[nt], o[jt]);
      }
    }
    __builtin_amdgcn_s_setprio(0);

    // counted-vmcnt barrier: stage(t+1) complete, stage(t+2) stays in flight.
    if (t < 30)      asm volatile("s_waitcnt vmcnt(2)" ::: "memory");
    else if (t < 31) asm volatile("s_waitcnt vmcnt(0)" ::: "memory");
    if (t < 31) __builtin_amdgcn_s_barrier();
  }

  // epilogue: normalize and write final f16. lane holds d = jt*16 + qd*4 + r
  // for row s = q0 + rl. Xo layout [B,S,D]: base (b*2048+s)*1024 + hh*64.
  {
    float lt = l_ + __shfl_xor(l_, 16);
    lt += __shfl_xor(lt, 32);
    const float inv = 1.0f / lt;
    const int b = bh >> 4, hh = bh & 15;
    const int s = q0 + rl;
    _Float16* xp = Xo + ((size_t)(b * 2048 + s)) * 1024 + hh * 64;
#pragma unroll
    for (int jt = 0; jt < 4; jt++) {
      f16x4 pk = {(_Float16)(o[jt][0] * inv), (_Float16)(o[jt][1] * inv),
                  (_Float16)(o[jt][2] * inv), (_Float16)(o[jt][3] * inv)};
      *(f16x4*)(xp + jt * 16 + qd * 4) = pk;
    }
  }
}

// ---------------- output projection: 64x128 tile, dbuf, fp32 out ----------------
// grid (64, 8): x = m-tile (XCD-clustering: 8 n-blocks sharing an A-panel have
// flat id m + 64n === m (mod 8) -> same XCD L2). r6-proven variant (async16 A
// staging -- r8's reg-staged merge fusion regressed at 2 blocks/CU).
__global__ __launch_bounds__(256, 2) void gemm_out(
    const _Float16* __restrict__ A0,
    const _Float16* __restrict__ W0,
    const float* __restrict__ bias,
    float* __restrict__ out)
{
  __shared__ _Float16 LA[2][2048];   // 64 x 32
  __shared__ _Float16 LB[2][4096];   // 128 x 32
  const int tid = threadIdx.x;
  const int lane = tid & 63;
  const int wv = tid >> 6;
  const int wm = wv >> 1, wn = wv & 1;
  const int rl = lane & 15, qd = lane >> 4;
  const int m0 = blockIdx.x * 64, n0 = blockIdx.y * 128;   // x=m, y=n (XCD cluster)

  f32x4 acc[2][4];
#pragma unroll
  for (int i = 0; i < 2; i++)
#pragma unroll
    for (int j = 0; j < 4; j++) acc[i][j] = f32x4{0.f, 0.f, 0.f, 0.f};

  auto stage = [&](int k0, int buf) {
    {  // A: 256 chunks, 1 per thread
      const int row = tid >> 2, c = tid & 3;
      async16(A0 + (size_t)(m0 + row) * 1024 + k0 + c * 8, &LA[buf][wv * 512]);
    }
#pragma unroll
    for (int it = 0; it < 2; it++) {  // B: 512 chunks, 2 per thread
      const int cI = it * 256 + tid;
      const int row = cI >> 2, c = cI & 3;
      async16(W0 + (size_t)(n0 + row) * 1024 + k0 + c * 8,
              &LB[buf][it * 2048 + wv * 512]);
    }
  };

  stage(0, 0);
  for (int t = 0; t < 32; t++) {
    const int buf = t & 1;
    __syncthreads();
    if (t + 1 < 32) stage((t + 1) * 32, buf ^ 1);
    f16x8 af[2], bfr[4];
#pragma unroll
    for (int i = 0; i < 2; i++) af[i] = *(const f16x8*)&LA[buf][(wm * 32 + i * 16 + rl) * 32 + qd * 8];
#pragma unroll
    for (int j = 0; j < 4; j++) bfr[j] = *(const f16x8*)&LB[buf][(wn * 64 + j * 16 + rl) * 32 + qd * 8];
#pragma unroll
    for (int i = 0; i < 2; i++)
#pragma unroll
      for (int j = 0; j < 4; j++) acc[i][j] = mfma_f16(af[i], bfr[j], acc[i][j]);
  }

#pragma unroll
  for (int j = 0; j < 4; j++) {
    const int nn = n0 + wn * 64 + j * 16 + rl;
    const float bj = bias[nn];
#pragma unroll
    for (int i = 0; i < 2; i++) {
      const int mm = m0 + wm * 32 + i * 16 + qd * 4;
#pragma unroll
      for (int r = 0; r < 4; r++)
        out[(size_t)(mm + r) * 1024 + nn] = acc[i][j][r] + bj;
    }
  }
}

// ---------------- launch ----------------
extern "C" void kernel_launch(void* const* d_in, const int* in_sizes, int n_in,
                              void* d_out, int out_size, void* d_ws, size_t ws_size,
                              hipStream_t stream) {
  const float* query = (const float*)d_in[0];
  const float* key   = (const float*)d_in[1];
  const float* value = (const float*)d_in[2];
  const float* Wq = (const float*)d_in[3];
  const float* bq = (const float*)d_in[4];
  const float* Wk = (const float*)d_in[5];
  const float* bk = (const float*)d_in[6];
  const float* Wv = (const float*)d_in[7];
  const float* bv = (const float*)d_in[8];
  const float* Wo = (const float*)d_in[9];
  const float* bo = (const float*)d_in[10];

  // workspace: f16 region 67 MB
  _Float16* ws = (_Float16*)d_ws;
  _Float16* Xf = ws;                          // 3*E8: query,key,value fp16
  _Float16* Wf = ws + 3 * (size_t)E8;         // 4*M1: Wq,Wk,Wv,Wo fp16
  _Float16* Qh = Wf + 4 * (size_t)M1;         // E8 [B,H,S,HD] (pre-scaled)
  _Float16* Kh = Qh + (size_t)E8;             // E8 [B,H,S,HD]
  _Float16* Vt = Kh + (size_t)E8;             // E8 [B,H,HD,S]
  _Float16* Xa = Vt + (size_t)E8;             // E8 [B,S,D]

  prep_all<<<8192, 256, 0, stream>>>(query, key, value, Wq, Wk, Wv, Wo, Xf, Wf);
  gemm_qkv<<<dim3(32, 8, 3), 256, 0, stream>>>(Xf, Wf, bq, bk, bv, Qh);
  attn_kernel<<<dim3(32, 16), 512, 0, stream>>>(Qh, Kh, Vt, Xa);
  gemm_out<<<dim3(64, 8), 256, 0, stream>>>(Xa, Wf + 3 * (size_t)M1, bo, (float*)d_out);
}